// Round 2
// baseline (523.810 us; speedup 1.0000x reference)
//
#include <hip/hip_runtime.h>
#include <math.h>

// Batched Kalman filter step: B=131072, STATE=16, OBS=8, fp32.
// v3: algebraic restructure — pred_cov = G cov G^T + W R W^T + Q with
// W = F*K, G = F - W*H (Joseph form folded through predict; new_cov never
// materialized). Consequences:
//   * every LDS write is a row-major b128 (NO scalar transpose writes ->
//     the 12M bank-conflict cycles of v2 disappear)
//   * cov and R never enter LDS (cov lives in covrow regs, R in rreg) ->
//     552 dwords/batch (v2: 616) -> 9216 B/block -> 17 blocks/CU
//   * epilogue matmul count drops from 4x(16x16x16)+extras to
//     W(128)+G(128)+T2(256)+pc(256+128)+RWt(128)
// Single-wave blocks (64 thr = 4 batches); all mid-phase buffer overlays
// rely on in-wave DS program order (proven pattern from v2).
//
// Per-batch LDS (dwords), stride 552 (== 8 mod 32: the 4 groups of a wave
// broadcast from disjoint bank quads):
//   Mb @   0 : 256  16x16 s16  G -> T2 (= cov*G^T)
//   Hb @ 256 : 128  8x16  s16
//   Xb @ 384 : 128  PHt(16x8 s8) -> S(8x8 s8) -> K(16x8 s8) -> W(16x8 s8)
//                   -> RWt(8x16 s16)
//   meanv @ 512 : 16 ;  rn @ 528 : 16 (resid(8) -> new_mean(16)) ; pad->552

#define NB 131072
#define BPB 4
#define THREADS 64
#define LDS_PER 552

typedef float vf4 __attribute__((ext_vector_type(4)));

#define ROW_FMA16(acc, s, base) do {                                        \
    const float4* _r = (const float4*)(base);                               \
    float4 _c0=_r[0], _c1=_r[1], _c2=_r[2], _c3=_r[3];                      \
    acc[0]+=(s)*_c0.x; acc[1]+=(s)*_c0.y; acc[2]+=(s)*_c0.z; acc[3]+=(s)*_c0.w; \
    acc[4]+=(s)*_c1.x; acc[5]+=(s)*_c1.y; acc[6]+=(s)*_c1.z; acc[7]+=(s)*_c1.w; \
    acc[8]+=(s)*_c2.x; acc[9]+=(s)*_c2.y; acc[10]+=(s)*_c2.z; acc[11]+=(s)*_c2.w; \
    acc[12]+=(s)*_c3.x; acc[13]+=(s)*_c3.y; acc[14]+=(s)*_c3.z; acc[15]+=(s)*_c3.w; \
} while (0)

#define ROW_FMA8(acc, s, base) do {                                         \
    const float4* _r = (const float4*)(base);                               \
    float4 _c0=_r[0], _c1=_r[1];                                            \
    acc[0]+=(s)*_c0.x; acc[1]+=(s)*_c0.y; acc[2]+=(s)*_c0.z; acc[3]+=(s)*_c0.w; \
    acc[4]+=(s)*_c1.x; acc[5]+=(s)*_c1.y; acc[6]+=(s)*_c1.z; acc[7]+=(s)*_c1.w; \
} while (0)

// res = dot(v[0:16], lds row at base) with 4 parallel partials
#define DOT16(res, v, base) do {                                            \
    const float4* _r = (const float4*)(base);                               \
    float4 _a=_r[0], _b=_r[1], _c=_r[2], _d=_r[3];                          \
    float _s0 = v[0]*_a.x + v[1]*_a.y + v[2]*_a.z + v[3]*_a.w;              \
    float _s1 = v[4]*_b.x + v[5]*_b.y + v[6]*_b.z + v[7]*_b.w;              \
    float _s2 = v[8]*_c.x + v[9]*_c.y + v[10]*_c.z + v[11]*_c.w;            \
    float _s3 = v[12]*_d.x + v[13]*_d.y + v[14]*_d.z + v[15]*_d.w;          \
    res = (_s0+_s1)+(_s2+_s3);                                              \
} while (0)

#define DOT8(res, v, base) do {                                             \
    const float4* _r = (const float4*)(base);                               \
    float4 _a=_r[0], _b=_r[1];                                              \
    float _s0 = v[0]*_a.x + v[1]*_a.y + v[2]*_a.z + v[3]*_a.w;              \
    float _s1 = v[4]*_b.x + v[5]*_b.y + v[6]*_b.z + v[7]*_b.w;              \
    res = _s0 + _s1;                                                        \
} while (0)

__global__ void __launch_bounds__(THREADS, 4)
kalman_step_kernel(const float* __restrict__ input, const float* __restrict__ mean,
                   const float* __restrict__ cov, const float* __restrict__ H,
                   const float* __restrict__ R, const float* __restrict__ F,
                   const float* __restrict__ Q,
                   float* __restrict__ out_mean, float* __restrict__ out_cov)
{
    __shared__ __align__(16) float lds[BPB * LDS_PER];

    const int tid = threadIdx.x;
    const int g = tid >> 4;        // batch slot (0..3)
    const int t = tid & 15;        // state row
    const long b = (long)blockIdx.x * BPB + g;

    float* Lb    = lds + g * LDS_PER;
    float* Mb    = Lb;             // G -> T2
    float* Hb    = Lb + 256;
    float* Xb    = Lb + 384;       // PHt -> S -> K -> W -> RWt
    float* meanv = Lb + 512;
    float* rn    = Lb + 528;

    // ---------------- Phase 1: global loads (cov regs-only, H, R, mean, input) ----------------
    float covrow[16];
    {
        const float4* C4 = (const float4*)(cov + b * 256 + t * 16);
        float4 c0 = C4[0], c1 = C4[1], c2 = C4[2], c3 = C4[3];
        covrow[0]=c0.x; covrow[1]=c0.y; covrow[2]=c0.z; covrow[3]=c0.w;
        covrow[4]=c1.x; covrow[5]=c1.y; covrow[6]=c1.z; covrow[7]=c1.w;
        covrow[8]=c2.x; covrow[9]=c2.y; covrow[10]=c2.z; covrow[11]=c2.w;
        covrow[12]=c3.x; covrow[13]=c3.y; covrow[14]=c3.z; covrow[15]=c3.w;
    }
    const float m = mean[b * 16 + t];
    meanv[t] = m;

    float hreg[16];
    float rreg[8];
    float inp = 0.0f;
    if (t < 8) {
        inp = input[b * 8 + t];
        const float4* H4 = (const float4*)(H + b * 128 + t * 16);
        float4 h0 = H4[0], h1 = H4[1], h2 = H4[2], h3 = H4[3];
        hreg[0]=h0.x; hreg[1]=h0.y; hreg[2]=h0.z; hreg[3]=h0.w;
        hreg[4]=h1.x; hreg[5]=h1.y; hreg[6]=h1.z; hreg[7]=h1.w;
        hreg[8]=h2.x; hreg[9]=h2.y; hreg[10]=h2.z; hreg[11]=h2.w;
        hreg[12]=h3.x; hreg[13]=h3.y; hreg[14]=h3.z; hreg[15]=h3.w;
        float4* hd = (float4*)(Hb + t * 16);
        hd[0]=h0; hd[1]=h1; hd[2]=h2; hd[3]=h3;
        const float4* R4 = (const float4*)(R + b * 64 + t * 8);
        float4 r0 = R4[0], r1 = R4[1];
        rreg[0]=r0.x; rreg[1]=r0.y; rreg[2]=r0.z; rreg[3]=r0.w;
        rreg[4]=r1.x; rreg[5]=r1.y; rreg[6]=r1.z; rreg[7]=r1.w;
    }
    __syncthreads();

    // ---------------- Phase 2: PHt row t = cov row . H rows ; resid ----------------
    float pht[8];
    #pragma unroll
    for (int o = 0; o < 8; ++o) {
        DOT16(pht[o], covrow, Hb + o * 16);
    }
    {
        float4* pd = (float4*)(Xb + t * 8);
        pd[0] = make_float4(pht[0], pht[1], pht[2], pht[3]);
        pd[1] = make_float4(pht[4], pht[5], pht[6], pht[7]);
    }
    if (t < 8) {
        float hm;
        DOT16(hm, hreg, meanv);
        rn[t] = inp - hm;
    }
    __syncthreads();

    // ---------------- Phase 3: S = H @ PHt + R (rows t<8), overwrites PHt[0:7] ----------------
    if (t < 8) {
        float sreg[8];
        #pragma unroll
        for (int c = 0; c < 8; ++c) sreg[c] = rreg[c];
        #pragma unroll
        for (int s = 0; s < 16; ++s) {
            float h = hreg[s];
            ROW_FMA8(sreg, h, Xb + s * 8);
        }
        float4* sd = (float4*)(Xb + t * 8);
        sd[0] = make_float4(sreg[0], sreg[1], sreg[2], sreg[3]);
        sd[1] = make_float4(sreg[4], sreg[5], sreg[6], sreg[7]);
    }
    __syncthreads();

    // ---------------- Phase 4: F prefetch; redundant Cholesky; K row; new_mean ----------------
    const float4* F4 = (const float4*)(F + b * 256 + t * 16);
    float4 fA = F4[0], fB = F4[1], fC = F4[2], fD = F4[3];

    float Lm[8][8];
    #pragma unroll
    for (int i = 0; i < 8; ++i) {
        const float4* sr = (const float4*)(Xb + i * 8);
        float4 s0 = sr[0], s1 = sr[1];
        Lm[i][0]=s0.x; Lm[i][1]=s0.y; Lm[i][2]=s0.z; Lm[i][3]=s0.w;
        Lm[i][4]=s1.x; Lm[i][5]=s1.y; Lm[i][6]=s1.z; Lm[i][7]=s1.w;
    }
    float dinv[8];
    #pragma unroll
    for (int k = 0; k < 8; ++k) {
        float diag = Lm[k][k];
        #pragma unroll
        for (int j = 0; j < k; ++j) diag -= Lm[k][j] * Lm[k][j];
        float lkk = sqrtf(diag);
        float inv = 1.0f / lkk;
        dinv[k] = inv;
        #pragma unroll
        for (int i = k + 1; i < 8; ++i) {
            float v = Lm[i][k];
            #pragma unroll
            for (int j = 0; j < k; ++j) v -= Lm[i][j] * Lm[k][j];
            Lm[i][k] = v * inv;
        }
    }
    float yv[8];
    #pragma unroll
    for (int i = 0; i < 8; ++i) {
        float v = pht[i];
        #pragma unroll
        for (int j = 0; j < i; ++j) v -= Lm[i][j] * yv[j];
        yv[i] = v * dinv[i];
    }
    float Kr[8];
    #pragma unroll
    for (int i = 7; i >= 0; --i) {
        float v = yv[i];
        #pragma unroll
        for (int j = i + 1; j < 8; ++j) v -= Lm[j][i] * Kr[j];
        Kr[i] = v * dinv[i];
    }
    // new_mean = m + K row . resid  (read resid, then overwrite rn[t])
    {
        const float4* rv = (const float4*)rn;
        float4 r0 = rv[0], r1 = rv[1];
        float nm = m;
        nm += Kr[0]*r0.x + Kr[1]*r0.y + Kr[2]*r0.z + Kr[3]*r0.w;
        nm += Kr[4]*r1.x + Kr[5]*r1.y + Kr[6]*r1.z + Kr[7]*r1.w;
        rn[t] = nm;
    }
    // K rows (16x8, s8) over Xb — row-major b128, no transpose
    {
        float4* kd = (float4*)(Xb + t * 8);
        kd[0] = make_float4(Kr[0], Kr[1], Kr[2], Kr[3]);
        kd[1] = make_float4(Kr[4], Kr[5], Kr[6], Kr[7]);
    }
    __syncthreads();

    // ---------------- Phase 5: W = F @ K (K rows broadcast); G = F - W @ H ----------------
    float freg[16];
    freg[0]=fA.x; freg[1]=fA.y; freg[2]=fA.z; freg[3]=fA.w;
    freg[4]=fB.x; freg[5]=fB.y; freg[6]=fB.z; freg[7]=fB.w;
    freg[8]=fC.x; freg[9]=fC.y; freg[10]=fC.z; freg[11]=fC.w;
    freg[12]=fD.x; freg[13]=fD.y; freg[14]=fD.z; freg[15]=fD.w;

    float Wr[8];
    #pragma unroll
    for (int c = 0; c < 8; ++c) Wr[c] = 0.0f;
    #pragma unroll
    for (int j = 0; j < 16; ++j) {
        float fj = freg[j];
        ROW_FMA8(Wr, fj, Xb + j * 8);
    }
    {   // W rows (16x8, s8) overwrite K (all reads above done; in-wave order)
        float4* wd = (float4*)(Xb + t * 8);
        wd[0] = make_float4(Wr[0], Wr[1], Wr[2], Wr[3]);
        wd[1] = make_float4(Wr[4], Wr[5], Wr[6], Wr[7]);
    }
    float Gr[16];
    #pragma unroll
    for (int j = 0; j < 16; ++j) Gr[j] = freg[j];
    #pragma unroll
    for (int o = 0; o < 8; ++o) {
        float nwo = -Wr[o];
        ROW_FMA16(Gr, nwo, Hb + o * 16);
    }
    {   // G rows (16x16, s16) -> Mb
        float4* gd = (float4*)(Mb + t * 16);
        gd[0] = make_float4(Gr[0], Gr[1], Gr[2], Gr[3]);
        gd[1] = make_float4(Gr[4], Gr[5], Gr[6], Gr[7]);
        gd[2] = make_float4(Gr[8], Gr[9], Gr[10], Gr[11]);
        gd[3] = make_float4(Gr[12], Gr[13], Gr[14], Gr[15]);
    }
    __syncthreads();

    // ---------------- Phase 6: Q prefetch; T2 = cov @ G^T (dots vs covrow regs) ----------------
    const float4* Q4 = (const float4*)(Q + b * 256 + t * 16);
    float4 qA = Q4[0], qB = Q4[1], qC = Q4[2], qD = Q4[3];

    float t2[16];
    #pragma unroll
    for (int c = 0; c < 16; ++c) {
        DOT16(t2[c], covrow, Mb + c * 16);
    }
    {   // T2 rows overwrite G in Mb (reads done; in-wave order)
        float4* td = (float4*)(Mb + t * 16);
        td[0] = make_float4(t2[0], t2[1], t2[2], t2[3]);
        td[1] = make_float4(t2[4], t2[5], t2[6], t2[7]);
        td[2] = make_float4(t2[8], t2[9], t2[10], t2[11]);
        td[3] = make_float4(t2[12], t2[13], t2[14], t2[15]);
    }
    __syncthreads();

    // ---------------- Phase 7: RWt = R @ W^T (rows t<8; dots vs rreg) ----------------
    if (t < 8) {
        float rw[16];
        #pragma unroll
        for (int c = 0; c < 16; ++c) {
            DOT8(rw[c], rreg, Xb + c * 8);
        }
        // RWt rows (8x16, s16) overwrite W region (reads done; in-wave order)
        float4* rd = (float4*)(Xb + t * 16);
        rd[0] = make_float4(rw[0], rw[1], rw[2], rw[3]);
        rd[1] = make_float4(rw[4], rw[5], rw[6], rw[7]);
        rd[2] = make_float4(rw[8], rw[9], rw[10], rw[11]);
        rd[3] = make_float4(rw[12], rw[13], rw[14], rw[15]);
    }
    __syncthreads();

    // ---------------- Phase 8: pred_cov row = Q + G.T2 + W.RWt ; pred_mean ----------------
    float pc[16];
    pc[0]=qA.x; pc[1]=qA.y; pc[2]=qA.z; pc[3]=qA.w;
    pc[4]=qB.x; pc[5]=qB.y; pc[6]=qB.z; pc[7]=qB.w;
    pc[8]=qC.x; pc[9]=qC.y; pc[10]=qC.z; pc[11]=qC.w;
    pc[12]=qD.x; pc[13]=qD.y; pc[14]=qD.z; pc[15]=qD.w;
    #pragma unroll
    for (int k = 0; k < 16; ++k) {
        float gk = Gr[k];
        ROW_FMA16(pc, gk, Mb + k * 16);     // T2 rows
    }
    #pragma unroll
    for (int o = 0; o < 8; ++o) {
        float wo = Wr[o];
        ROW_FMA16(pc, wo, Xb + o * 16);     // RWt rows
    }
    float pm;
    DOT16(pm, freg, rn);                     // F row . new_mean

    // ---------------- Stores (nontemporal: outputs never re-read) ----------------
    __builtin_nontemporal_store(pm, &out_mean[b * 16 + t]);
    {
        vf4* od = (vf4*)(out_cov + b * 256 + t * 16);
        vf4 v0 = {pc[0], pc[1], pc[2], pc[3]};
        vf4 v1 = {pc[4], pc[5], pc[6], pc[7]};
        vf4 v2 = {pc[8], pc[9], pc[10], pc[11]};
        vf4 v3 = {pc[12], pc[13], pc[14], pc[15]};
        __builtin_nontemporal_store(v0, od + 0);
        __builtin_nontemporal_store(v1, od + 1);
        __builtin_nontemporal_store(v2, od + 2);
        __builtin_nontemporal_store(v3, od + 3);
    }
}

extern "C" void kernel_launch(void* const* d_in, const int* in_sizes, int n_in,
                              void* d_out, int out_size, void* d_ws, size_t ws_size,
                              hipStream_t stream) {
    const float* input = (const float*)d_in[0];
    const float* mean  = (const float*)d_in[1];
    const float* cov   = (const float*)d_in[2];
    const float* H     = (const float*)d_in[3];
    const float* R     = (const float*)d_in[4];
    const float* F     = (const float*)d_in[5];
    const float* Q     = (const float*)d_in[6];
    float* out = (float*)d_out;
    float* out_mean = out;
    float* out_cov  = out + (size_t)NB * 16;

    dim3 grid(NB / BPB);
    dim3 block(THREADS);
    hipLaunchKernelGGL(kalman_step_kernel, grid, block, 0, stream,
                       input, mean, cov, H, R, F, Q, out_mean, out_cov);
}